// Round 19
// baseline (146.443 us; speedup 1.0000x reference)
//
#include <hip/hip_runtime.h>
#include <hip/hip_bf16.h>

typedef __attribute__((ext_vector_type(8))) short short8;
typedef __attribute__((ext_vector_type(4))) short short4v;
typedef __attribute__((ext_vector_type(4))) float float4v;

#define DEV __device__ __forceinline__

constexpr int SEQ = 1024;
constexpr int DM  = 1024;    // d_model
constexpr int KVD = 256;     // kv dim
constexpr int MTOK = 4096;   // batch*seq

// 1/sqrt(32) * log2(e) — folded into Q so softmax uses raw v_exp_f32 (2^x)
constexpr float QSCALE = 0.25503487660444f;

// ---- helpers ----------------------------------------------------------------

DEV void load_lds16(const void* g, void* l) {
  __builtin_amdgcn_global_load_lds(
      (const __attribute__((address_space(1))) unsigned int*)g,
      (__attribute__((address_space(3))) unsigned int*)l, 16, 0, 0);
}

DEV unsigned short f2bf(float f) {   // fp32 -> bf16 RNE
  unsigned int u = __float_as_uint(f);
  u += 0x7fffu + ((u >> 16) & 1u);
  return (unsigned short)(u >> 16);
}

DEV float fexp2(float x) {           // raw 2^x
  float y;
  asm("v_exp_f32 %0, %1" : "=v"(y) : "v"(x));
  return y;
}

DEV unsigned int cvtpk(float lo, float hi) {   // pack 2 f32 -> 2 bf16 (lo->[15:0])
  unsigned int r;
  asm("v_cvt_pk_bf16_f32 %0, %1, %2" : "=v"(r) : "v"(lo), "v"(hi));
  return r;
}

#if __has_builtin(__builtin_amdgcn_mfma_f32_16x16x16bf16_1k)
DEV float4v mfma16(short4v a, short4v b, float4v c) {
  return __builtin_amdgcn_mfma_f32_16x16x16bf16_1k(a, b, c, 0, 0, 0);
}
#else
DEV float4v mfma16(short4v a, short4v b, float4v c) {
  asm("v_mfma_f32_16x16x16_bf16 %0, %1, %2, %0" : "+v"(c) : "v"(a), "v"(b));
  return c;
}
#endif

#define WAIT_VM(N)  asm volatile("s_waitcnt vmcnt(" #N ")" ::: "memory")
#define WAIT_LG(N)  asm volatile("s_waitcnt lgkmcnt(" #N ")" ::: "memory")
#define WAIT_LGKM0  asm volatile("s_waitcnt lgkmcnt(0)" ::: "memory")
#define SBAR0       __builtin_amdgcn_sched_barrier(0)

// ---- prep: fp32->bf16 conversions + rope table ------------------------------

__global__ __launch_bounds__(256)
void prep_kernel(const float* __restrict__ x,  const float* __restrict__ Wq,
                 const float* __restrict__ Wk, const float* __restrict__ Wv,
                 const float* __restrict__ Wo,
                 unsigned short* __restrict__ xb, unsigned short* __restrict__ Wqkvb,
                 unsigned short* __restrict__ Wob,
                 float* __restrict__ rc, float* __restrict__ rs)
{
  const int NX  = (MTOK*DM)/4;          // 1048576
  const int NWQ = (DM*DM)/4;            // 262144
  const int NWK = (KVD*DM)/4;           // 65536
  const int NCONV = NX + NWQ + 2*NWK + NWQ; // 1703936
  int id = blockIdx.x*256 + threadIdx.x;
  if (id < NCONV) {
    const float* src; unsigned short* dst; int u;
    if      (id < NX)            { src = x;  dst = xb;                     u = id; }
    else if (id < NX+NWQ)        { src = Wq; dst = Wqkvb;                  u = id-NX; }
    else if (id < NX+NWQ+NWK)    { src = Wk; dst = Wqkvb + DM*DM;          u = id-(NX+NWQ); }
    else if (id < NX+NWQ+2*NWK)  { src = Wv; dst = Wqkvb + DM*DM+KVD*DM;   u = id-(NX+NWQ+NWK); }
    else                         { src = Wo; dst = Wob;                    u = id-(NX+NWQ+2*NWK); }
    float4 v = ((const float4*)src)[u];
    ushort4 o;
    o.x = f2bf(v.x); o.y = f2bf(v.y); o.z = f2bf(v.z); o.w = f2bf(v.w);
    ((ushort4*)dst)[u] = o;
  } else {
    int id2 = id - NCONV;                 // [0, 1024*512)
    if (id2 < SEQ*512) {
      int pos = id2 >> 9, i = id2 & 511;
      float theta = exp2f((float)i * (-13.287712379549449f/512.0f));
      float ang = (float)pos * theta;
      float sv, cv; sincosf(ang, &sv, &cv);
      rc[id2] = cv; rs[id2] = sv;
    }
  }
}

// ---- NT bf16 MFMA GEMM: C[m][n] = sum_k A[m][k]*B[n][k] ---------------------
// 128x64 tile, BK=64, 4 waves (2x2; wave 64x32). 2-deep LDS buffer, counted
// vmcnt (steady 6, never 0 mid-loop). Intra-step ksub split: MFMA(ksub0)
// overlaps ds_reads(ksub1) via lgkmcnt(6); stage(kt+2) issued after barrier#2
// overlaps MFMA(ksub1). Swizzle chunk^(row&7) -> 2-way/phase (free), applied
// to BOTH global source and LDS read (rule #21).
// MODE 0: fused QKV epilogue (rope+prescale Q -> Qb, rope K -> Kb, V -> Vt)
// MODE 2: out-projection epilogue (fp32 + bias -> outF)

template<int MODE, int GY>
__global__ __launch_bounds__(256)
void gemm_nt(const unsigned short* __restrict__ A, const unsigned short* __restrict__ Bw,
             unsigned short* __restrict__ outQ, unsigned short* __restrict__ outK,
             unsigned short* __restrict__ outVt, float* __restrict__ outF,
             const float* __restrict__ bias,
             const float* __restrict__ rc, const float* __restrict__ rs)
{
  __shared__ __align__(16) unsigned short As[2][128*64];   // 32 KB
  __shared__ __align__(16) unsigned short Bs[2][64*64];    // 16 KB
  const int tid = threadIdx.x;
  const int w  = tid >> 6, l = tid & 63;
  const int lg = l >> 4, ll = l & 15;
  const int wr = w >> 1, wc = w & 1;

  // XCD-aware bijective swizzle (nwg = 32*GY, divisible by 8), M-major chunks
  const int bid = (int)blockIdx.x;
  const int f   = (bid & 7) * (4*GY) + (bid >> 3);
  const int brow = (f / GY) * 128, bcol = (f % GY) * 64;

  float4v acc[4][2];
#pragma unroll
  for (int i = 0; i < 4; ++i)
#pragma unroll
    for (int j = 0; j < 2; ++j) acc[i][j] = (float4v){0.f,0.f,0.f,0.f};

  auto stage = [&](int kt, int cur) {
#pragma unroll
    for (int blk = 0; blk < 4; ++blk) {    // A: 1024 chunks (128 rows x 8)
      int cid = blk*256 + w*64 + l;
      int row = cid >> 3, c = cid & 7;
      int cg = c ^ (row & 7);              // involution, pre-applied to source
      load_lds16(A + (size_t)(brow+row)*DM + kt*64 + cg*8,
                 &As[cur][(blk*256 + w*64)*8]);
    }
#pragma unroll
    for (int blk = 0; blk < 2; ++blk) {    // B: 512 chunks (64 rows x 8)
      int cid = blk*256 + w*64 + l;
      int row = cid >> 3, c = cid & 7;
      int cg = c ^ (row & 7);
      load_lds16(Bw + (size_t)(bcol+row)*DM + kt*64 + cg*8,
                 &Bs[cur][(blk*256 + w*64)*8]);
    }
  };

  stage(0, 0); stage(1, 1);                // 12 loads/thread in flight
#pragma unroll 1
  for (int kt = 0; kt < 16; ++kt) {
    const int cur = kt & 1;
    if (kt < 15) { WAIT_VM(6); }           // retire stage kt; kt+1 stays in flight
    else         { WAIT_VM(0); }
    __builtin_amdgcn_s_barrier();          // buffer cur fully staged (all waves)

    short8 af[2][4], bf[2][2];
    // ksub0 reads (6)
#pragma unroll
    for (int mi = 0; mi < 4; ++mi) {
      int row = wr*64 + mi*16 + ll;
      af[0][mi] = *(const short8*)&As[cur][row*64 + ((lg ^ (row & 7)) << 3)];
    }
#pragma unroll
    for (int ni = 0; ni < 2; ++ni) {
      int col = wc*32 + ni*16 + ll;
      bf[0][ni] = *(const short8*)&Bs[cur][col*64 + ((lg ^ (col & 7)) << 3)];
    }
    SBAR0;                                 // pin: ksub0 reads issue first
    // ksub1 reads (6)
#pragma unroll
    for (int mi = 0; mi < 4; ++mi) {
      int row = wr*64 + mi*16 + ll;
      af[1][mi] = *(const short8*)&As[cur][row*64 + (((4 + lg) ^ (row & 7)) << 3)];
    }
#pragma unroll
    for (int ni = 0; ni < 2; ++ni) {
      int col = wc*32 + ni*16 + ll;
      bf[1][ni] = *(const short8*)&Bs[cur][col*64 + (((4 + lg) ^ (col & 7)) << 3)];
    }
    WAIT_LG(6);                            // ksub0 ready (DS in-order)
    SBAR0;
    __builtin_amdgcn_s_setprio(1);
#pragma unroll
    for (int mi = 0; mi < 4; ++mi)
#pragma unroll
      for (int ni = 0; ni < 2; ++ni)
        acc[mi][ni] = __builtin_amdgcn_mfma_f32_16x16x32_bf16(af[0][mi], bf[0][ni], acc[mi][ni], 0,0,0);
    __builtin_amdgcn_s_setprio(0);
    SBAR0;
    WAIT_LGKM0;                            // ksub1 ready; all reads of cur done
    SBAR0;
    __builtin_amdgcn_s_barrier();          // all waves done reading buffer cur

    if (kt + 2 < 16) stage(kt + 2, cur);   // refill freed buffer (overlaps below)

    __builtin_amdgcn_s_setprio(1);
#pragma unroll
    for (int mi = 0; mi < 4; ++mi)
#pragma unroll
      for (int ni = 0; ni < 2; ++ni)
        acc[mi][ni] = __builtin_amdgcn_mfma_f32_16x16x32_bf16(af[1][mi], bf[1][ni], acc[mi][ni], 0,0,0);
    __builtin_amdgcn_s_setprio(0);
  }

  // epilogue: C/D layout col=lane&15, row=(lane>>4)*4+r
#pragma unroll
  for (int mi = 0; mi < 4; ++mi)
#pragma unroll
    for (int ni = 0; ni < 2; ++ni)
#pragma unroll
      for (int r = 0; r < 4; ++r) {
        int m = brow + wr*64 + mi*16 + lg*4 + r;
        int n = bcol + wc*32 + ni*16 + ll;
        float v = acc[mi][ni][r];
        if constexpr (MODE == 0) {
          float p = __shfl_xor(v, 1);      // rope partner col n^1 = lane l^1
          if (n < DM) {                    // Q
            int pos = m & (SEQ-1);
            int i = n >> 1;
            float ct = rc[pos*512 + i], st = rs[pos*512 + i];
            v = (n & 1) ? (v*ct + p*st) : (v*ct - p*st);
            outQ[(size_t)m*DM + n] = f2bf(v * QSCALE);
          } else if (n < DM + KVD) {       // K
            int nk = n - DM;
            int pos = m & (SEQ-1);
            int i = nk >> 1;
            float ct = rc[pos*512 + i], st = rs[pos*512 + i];
            v = (nk & 1) ? (v*ct + p*st) : (v*ct - p*st);
            outK[(size_t)m*KVD + nk] = f2bf(v);
          } else {                         // V -> transposed Vt[b][nv][s]
            int nv = n - DM - KVD;
            outVt[((size_t)(m >> 10)*KVD + nv)*SEQ + (m & (SEQ-1))] = f2bf(v);
          }
        } else {
          outF[(size_t)m*DM + n] = v + bias[n];
        }
      }
}

// ---- causal GQA flash attention v16: barrier-free, LDS-free, L2-direct ------
// R8 retried in the current regime: fixed-ref softmax (no cross-lane chains),
// XCD-local K/V (x = b*8+hk -> XCD = hk; 128KB/set, L2-resident), lean state
// (~108 VGPR -> 4 waves/SIMD, 2x R8's TLP). Each wave fully independent: no
// barriers, no LDS, no staging. K 2-deep register prefetch (manual A/B unroll,
// static indexing); V loaded at compute-top (latency hidden under QK MFMA+exp).
// Pairing (63-y, y): uniformly 17 kv-iterations of 64 per block.

__global__ __launch_bounds__(256, 4)
void attn_kernel(const unsigned short* __restrict__ Qb, const unsigned short* __restrict__ Kb,
                 const unsigned short* __restrict__ Vtb, unsigned short* __restrict__ Ob)
{
  const int tid = threadIdx.x;
  const int w  = tid >> 6, l = tid & 63;
  const int lg = l >> 4, ll = l & 15;
  const int hk = (int)blockIdx.x & 7, b = (int)blockIdx.x >> 3;
  const int h  = hk*4 + w;

  // per-lane bases: K row = ll (16B chunk lg); V row d = ll (+16 for df=1)
  const unsigned short* Kh = Kb  + ((size_t)b*SEQ + ll)*KVD + hk*32 + (lg<<3);
  const unsigned short* Vh = Vtb + ((size_t)b*KVD + hk*32 + ll)*SEQ + (lg<<2);

#pragma unroll 1
  for (int ph = 0; ph < 2; ++ph) {
    const int qt = ph ? (int)blockIdx.y : 63 - (int)blockIdx.y;   // 16-row tile
    const int nt = (qt + 4) >> 2;         // 64-wide kv tiles needed (causal)
    const int q0 = qt*16;

    // Q as B-operand frag: col q = ll, k = d = lg*8+j  (pre-scaled by QSCALE)
    short8 qf = *(const short8*)&Qb[((size_t)b*SEQ + q0 + ll)*DM + h*32 + (lg<<3)];

    float4v o[2];                         // O^T frag [df]: d=df*16+lg*4+r, q=ll
    float lrow = 0.f;
    o[0] = (float4v){0,0,0,0}; o[1] = (float4v){0,0,0,0};

    auto ldK = [&](short8 (&kf)[4], int kvt) {
#pragma unroll
      for (int ni = 0; ni < 4; ++ni)      // kv row = kvt*64 + ni*16 + ll
        kf[ni] = *(const short8*)&Kh[(size_t)(kvt*64 + ni*16)*KVD];
    };

    auto compute = [&](const short8 (&kf)[4], int kvt) {
      // V fragments for this tile (latency hidden under QK MFMA + exp)
      short4v vf[2][4];
#pragma unroll
      for (int df = 0; df < 2; ++df)
#pragma unroll
        for (int ni = 0; ni < 4; ++ni)    // kv = kvt*64 + ni*16 + lg*4, d = df*16+ll
          vf[df][ni] = *(const short4v*)&Vh[(size_t)(df*16)*SEQ + kvt*64 + ni*16];

      // ---- S^T = K Q^T : lane holds col q=ll, rows kv = ni*16+lg*4+r
      float sc[4][4];
      __builtin_amdgcn_s_setprio(1);
#pragma unroll
      for (int ni = 0; ni < 4; ++ni) {
        float4v s = __builtin_amdgcn_mfma_f32_16x16x32_bf16(kf[ni], qf,
                       (float4v){0,0,0,0}, 0,0,0);
#pragma unroll
        for (int r = 0; r < 4; ++r) sc[ni][r] = s[r];
      }
      __builtin_amdgcn_s_setprio(0);

      if (kvt == nt-1) {                  // causal mask (only last tile)
        int q = q0 + ll;
#pragma unroll
        for (int ni = 0; ni < 4; ++ni)
#pragma unroll
          for (int r = 0; r < 4; ++r) {
            int kv = kvt*64 + ni*16 + lg*4 + r;
            if (kv > q) sc[ni][r] = -1e30f;
          }
      }

      // ---- fixed-reference softmax: P = 2^s, per-lane only (no reduces)
      float s0 = 0.f;
      short4v pf[4];
#pragma unroll
      for (int ni = 0; ni < 4; ++ni) {
        float p0 = fexp2(sc[ni][0]);
        float p1 = fexp2(sc[ni][1]);
        float p2 = fexp2(sc[ni][2]);
        float p3 = fexp2(sc[ni][3]);
        s0 += (p0 + p1) + (p2 + p3);
        union { unsigned int u[2]; short4v s4; } cv;
        cv.u[0] = cvtpk(p0, p1); cv.u[1] = cvtpk(p2, p3);
        pf[ni] = cv.s4;
      }
      lrow += s0;

      // ---- O^T += V^T P
      __builtin_amdgcn_s_setprio(1);
#pragma unroll
      for (int df = 0; df < 2; ++df)
#pragma unroll
        for (int ni = 0; ni < 4; ++ni)
          o[df] = mfma16(vf[df][ni], pf[ni], o[df]);
      __builtin_amdgcn_s_setprio(0);
    };

    // 2-deep K register pipeline, manual A/B unroll (static reg indexing)
    short8 kfA[4], kfB[4];
    ldK(kfA, 0);
    int kvt = 0;
    while (true) {
      if (kvt + 1 < nt) ldK(kfB, kvt+1);
      compute(kfA, kvt);
      ++kvt; if (kvt >= nt) break;
      if (kvt + 1 < nt) ldK(kfA, kvt+1);
      compute(kfB, kvt);
      ++kvt; if (kvt >= nt) break;
    }

    // deferred row-sum reduction (across lg only) + normalized store
    float s = lrow;
    s += __shfl_xor(s, 16);
    s += __shfl_xor(s, 32);
    float inv = 1.f / s;
    size_t tok = (size_t)b*SEQ + q0 + ll;
#pragma unroll
    for (int df = 0; df < 2; ++df) {
      short4v sv;
#pragma unroll
      for (int r = 0; r < 4; ++r) sv[r] = (short)f2bf(o[df][r] * inv);
      *(short4v*)&Ob[tok*DM + h*32 + df*16 + lg*4] = sv;
    }
  }
}

// ---- launch -----------------------------------------------------------------

extern "C" void kernel_launch(void* const* d_in, const int* in_sizes, int n_in,
                              void* d_out, int out_size, void* d_ws, size_t ws_size,
                              hipStream_t stream)
{
  const float* x  = (const float*)d_in[0];
  const float* Wq = (const float*)d_in[1];
  const float* Wk = (const float*)d_in[2];
  const float* Wv = (const float*)d_in[3];
  const float* Wo = (const float*)d_in[4];
  const float* bo = (const float*)d_in[5];
  float* out = (float*)d_out;

  char* ws = (char*)d_ws;
  const size_t MB = 1u << 20;
  unsigned short* xb    = (unsigned short*)(ws + 0*MB);   // 8 MB
  unsigned short* Wqkvb = (unsigned short*)(ws + 8*MB);   // 3 MB [1536][1024]
  unsigned short* Wob   = (unsigned short*)(ws + 11*MB);  // 2 MB
  float*          rc    = (float*)(ws + 13*MB);           // 2 MB [1024][512]
  float*          rs    = (float*)(ws + 15*MB);           // 2 MB
  unsigned short* Qb    = (unsigned short*)(ws + 17*MB);  // 8 MB [4096][1024]
  unsigned short* Kb    = (unsigned short*)(ws + 25*MB);  // 2 MB [4096][256]
  unsigned short* Vt    = (unsigned short*)(ws + 27*MB);  // 2 MB [4][256][1024]
  unsigned short* Ob    = (unsigned short*)(ws + 29*MB);  // 8 MB [4096][1024]
  if (ws_size < 37*MB) return;

  {
    const int total = 1703936 + SEQ*512;
    const int blocks = (total + 255) / 256;
    prep_kernel<<<blocks, 256, 0, stream>>>(x, Wq, Wk, Wv, Wo, xb, Wqkvb, Wob, rc, rs);
  }
  // QKV: N=1536 -> GY=24, 768 blocks (3/CU at 48KB LDS)
  gemm_nt<0, 24><<<dim3(768), 256, 0, stream>>>(xb, Wqkvb, Qb, Kb, Vt, nullptr, nullptr, rc, rs);
  // attn: grid x = b*8+hk (XCD = hk), y = pair index
  attn_kernel<<<dim3(32, 32), 256, 0, stream>>>(Qb, Kb, Vt, Ob);
  // out-proj: N=1024 -> GY=16, 512 blocks
  gemm_nt<2, 16><<<dim3(512), 256, 0, stream>>>(Ob, Wob, nullptr, nullptr, nullptr, out, bo, rc, rs);
}

// Round 20
// 77.449 us; speedup vs baseline: 1.8908x; 1.8908x over previous
//
#include <hip/hip_runtime.h>
#include <hip/hip_bf16.h>

typedef __attribute__((ext_vector_type(8))) short short8;
typedef __attribute__((ext_vector_type(4))) short short4v;
typedef __attribute__((ext_vector_type(4))) float float4v;

#define DEV __device__ __forceinline__

constexpr int SEQ = 1024;
constexpr int DM  = 1024;    // d_model
constexpr int KVD = 256;     // kv dim
constexpr int MTOK = 4096;   // batch*seq

// 1/sqrt(32) * log2(e) — folded into Q so softmax uses raw v_exp_f32 (2^x)
constexpr float QSCALE = 0.25503487660444f;

// ---- helpers ----------------------------------------------------------------

DEV void load_lds16(const void* g, void* l) {
  __builtin_amdgcn_global_load_lds(
      (const __attribute__((address_space(1))) unsigned int*)g,
      (__attribute__((address_space(3))) unsigned int*)l, 16, 0, 0);
}

DEV unsigned short f2bf(float f) {   // fp32 -> bf16 RNE
  unsigned int u = __float_as_uint(f);
  u += 0x7fffu + ((u >> 16) & 1u);
  return (unsigned short)(u >> 16);
}

DEV float fexp2(float x) {           // raw 2^x
  float y;
  asm("v_exp_f32 %0, %1" : "=v"(y) : "v"(x));
  return y;
}

DEV unsigned int cvtpk(float lo, float hi) {   // pack 2 f32 -> 2 bf16 (lo->[15:0])
  unsigned int r;
  asm("v_cvt_pk_bf16_f32 %0, %1, %2" : "=v"(r) : "v"(lo), "v"(hi));
  return r;
}

#if __has_builtin(__builtin_amdgcn_mfma_f32_16x16x16bf16_1k)
DEV float4v mfma16(short4v a, short4v b, float4v c) {
  return __builtin_amdgcn_mfma_f32_16x16x16bf16_1k(a, b, c, 0, 0, 0);
}
#else
DEV float4v mfma16(short4v a, short4v b, float4v c) {
  asm("v_mfma_f32_16x16x16_bf16 %0, %1, %2, %0" : "+v"(c) : "v"(a), "v"(b));
  return c;
}
#endif

#define WAIT_VM(N)  asm volatile("s_waitcnt vmcnt(" #N ")" ::: "memory")
#define WAIT_LG(N)  asm volatile("s_waitcnt lgkmcnt(" #N ")" ::: "memory")
#define WAIT_LGKM0  asm volatile("s_waitcnt lgkmcnt(0)" ::: "memory")
#define SBAR0       __builtin_amdgcn_sched_barrier(0)

// ---- prep: fp32->bf16 conversions + rope table ------------------------------

__global__ __launch_bounds__(256)
void prep_kernel(const float* __restrict__ x,  const float* __restrict__ Wq,
                 const float* __restrict__ Wk, const float* __restrict__ Wv,
                 const float* __restrict__ Wo,
                 unsigned short* __restrict__ xb, unsigned short* __restrict__ Wqkvb,
                 unsigned short* __restrict__ Wob,
                 float* __restrict__ rc, float* __restrict__ rs)
{
  const int NX  = (MTOK*DM)/4;          // 1048576
  const int NWQ = (DM*DM)/4;            // 262144
  const int NWK = (KVD*DM)/4;           // 65536
  const int NCONV = NX + NWQ + 2*NWK + NWQ; // 1703936
  int id = blockIdx.x*256 + threadIdx.x;
  if (id < NCONV) {
    const float* src; unsigned short* dst; int u;
    if      (id < NX)            { src = x;  dst = xb;                     u = id; }
    else if (id < NX+NWQ)        { src = Wq; dst = Wqkvb;                  u = id-NX; }
    else if (id < NX+NWQ+NWK)    { src = Wk; dst = Wqkvb + DM*DM;          u = id-(NX+NWQ); }
    else if (id < NX+NWQ+2*NWK)  { src = Wv; dst = Wqkvb + DM*DM+KVD*DM;   u = id-(NX+NWQ+NWK); }
    else                         { src = Wo; dst = Wob;                    u = id-(NX+NWQ+2*NWK); }
    float4 v = ((const float4*)src)[u];
    ushort4 o;
    o.x = f2bf(v.x); o.y = f2bf(v.y); o.z = f2bf(v.z); o.w = f2bf(v.w);
    ((ushort4*)dst)[u] = o;
  } else {
    int id2 = id - NCONV;                 // [0, 1024*512)
    if (id2 < SEQ*512) {
      int pos = id2 >> 9, i = id2 & 511;
      float theta = exp2f((float)i * (-13.287712379549449f/512.0f));
      float ang = (float)pos * theta;
      float sv, cv; sincosf(ang, &sv, &cv);
      rc[id2] = cv; rs[id2] = sv;
    }
  }
}

// ---- NT bf16 MFMA GEMM: C[m][n] = sum_k A[m][k]*B[n][k] ---------------------
// 128x64 tile, BK=64, 4 waves (2x2; wave 64x32). 2-deep LDS buffer, counted
// vmcnt (steady 6, never 0 mid-loop). Intra-step ksub split: MFMA(ksub0)
// overlaps ds_reads(ksub1) via lgkmcnt(6); stage(kt+2) issued after barrier#2
// overlaps MFMA(ksub1). Swizzle chunk^(row&7) -> 2-way/phase (free), applied
// to BOTH global source and LDS read (rule #21).
// MODE 0: fused QKV epilogue (rope+prescale Q -> Qb, rope K -> Kb, V -> Vt)
// MODE 2: out-projection epilogue (fp32 + bias -> outF)

template<int MODE, int GY>
__global__ __launch_bounds__(256)
void gemm_nt(const unsigned short* __restrict__ A, const unsigned short* __restrict__ Bw,
             unsigned short* __restrict__ outQ, unsigned short* __restrict__ outK,
             unsigned short* __restrict__ outVt, float* __restrict__ outF,
             const float* __restrict__ bias,
             const float* __restrict__ rc, const float* __restrict__ rs)
{
  __shared__ __align__(16) unsigned short As[2][128*64];   // 32 KB
  __shared__ __align__(16) unsigned short Bs[2][64*64];    // 16 KB
  const int tid = threadIdx.x;
  const int w  = tid >> 6, l = tid & 63;
  const int lg = l >> 4, ll = l & 15;
  const int wr = w >> 1, wc = w & 1;

  // XCD-aware bijective swizzle (nwg = 32*GY, divisible by 8), M-major chunks
  const int bid = (int)blockIdx.x;
  const int f   = (bid & 7) * (4*GY) + (bid >> 3);
  const int brow = (f / GY) * 128, bcol = (f % GY) * 64;

  float4v acc[4][2];
#pragma unroll
  for (int i = 0; i < 4; ++i)
#pragma unroll
    for (int j = 0; j < 2; ++j) acc[i][j] = (float4v){0.f,0.f,0.f,0.f};

  auto stage = [&](int kt, int cur) {
#pragma unroll
    for (int blk = 0; blk < 4; ++blk) {    // A: 1024 chunks (128 rows x 8)
      int cid = blk*256 + w*64 + l;
      int row = cid >> 3, c = cid & 7;
      int cg = c ^ (row & 7);              // involution, pre-applied to source
      load_lds16(A + (size_t)(brow+row)*DM + kt*64 + cg*8,
                 &As[cur][(blk*256 + w*64)*8]);
    }
#pragma unroll
    for (int blk = 0; blk < 2; ++blk) {    // B: 512 chunks (64 rows x 8)
      int cid = blk*256 + w*64 + l;
      int row = cid >> 3, c = cid & 7;
      int cg = c ^ (row & 7);
      load_lds16(Bw + (size_t)(bcol+row)*DM + kt*64 + cg*8,
                 &Bs[cur][(blk*256 + w*64)*8]);
    }
  };

  stage(0, 0); stage(1, 1);                // 12 loads/thread in flight
#pragma unroll 1
  for (int kt = 0; kt < 16; ++kt) {
    const int cur = kt & 1;
    if (kt < 15) { WAIT_VM(6); }           // retire stage kt; kt+1 stays in flight
    else         { WAIT_VM(0); }
    __builtin_amdgcn_s_barrier();          // buffer cur fully staged (all waves)

    short8 af[2][4], bf[2][2];
    // ksub0 reads (6)
#pragma unroll
    for (int mi = 0; mi < 4; ++mi) {
      int row = wr*64 + mi*16 + ll;
      af[0][mi] = *(const short8*)&As[cur][row*64 + ((lg ^ (row & 7)) << 3)];
    }
#pragma unroll
    for (int ni = 0; ni < 2; ++ni) {
      int col = wc*32 + ni*16 + ll;
      bf[0][ni] = *(const short8*)&Bs[cur][col*64 + ((lg ^ (col & 7)) << 3)];
    }
    SBAR0;                                 // pin: ksub0 reads issue first
    // ksub1 reads (6)
#pragma unroll
    for (int mi = 0; mi < 4; ++mi) {
      int row = wr*64 + mi*16 + ll;
      af[1][mi] = *(const short8*)&As[cur][row*64 + (((4 + lg) ^ (row & 7)) << 3)];
    }
#pragma unroll
    for (int ni = 0; ni < 2; ++ni) {
      int col = wc*32 + ni*16 + ll;
      bf[1][ni] = *(const short8*)&Bs[cur][col*64 + (((4 + lg) ^ (col & 7)) << 3)];
    }
    WAIT_LG(6);                            // ksub0 ready (DS in-order)
    SBAR0;
    __builtin_amdgcn_s_setprio(1);
#pragma unroll
    for (int mi = 0; mi < 4; ++mi)
#pragma unroll
      for (int ni = 0; ni < 2; ++ni)
        acc[mi][ni] = __builtin_amdgcn_mfma_f32_16x16x32_bf16(af[0][mi], bf[0][ni], acc[mi][ni], 0,0,0);
    __builtin_amdgcn_s_setprio(0);
    SBAR0;
    WAIT_LGKM0;                            // ksub1 ready; all reads of cur done
    SBAR0;
    __builtin_amdgcn_s_barrier();          // all waves done reading buffer cur

    if (kt + 2 < 16) stage(kt + 2, cur);   // refill freed buffer (overlaps below)

    __builtin_amdgcn_s_setprio(1);
#pragma unroll
    for (int mi = 0; mi < 4; ++mi)
#pragma unroll
      for (int ni = 0; ni < 2; ++ni)
        acc[mi][ni] = __builtin_amdgcn_mfma_f32_16x16x32_bf16(af[1][mi], bf[1][ni], acc[mi][ni], 0,0,0);
    __builtin_amdgcn_s_setprio(0);
  }

  // epilogue: C/D layout col=lane&15, row=(lane>>4)*4+r
#pragma unroll
  for (int mi = 0; mi < 4; ++mi)
#pragma unroll
    for (int ni = 0; ni < 2; ++ni)
#pragma unroll
      for (int r = 0; r < 4; ++r) {
        int m = brow + wr*64 + mi*16 + lg*4 + r;
        int n = bcol + wc*32 + ni*16 + ll;
        float v = acc[mi][ni][r];
        if constexpr (MODE == 0) {
          float p = __shfl_xor(v, 1);      // rope partner col n^1 = lane l^1
          if (n < DM) {                    // Q
            int pos = m & (SEQ-1);
            int i = n >> 1;
            float ct = rc[pos*512 + i], st = rs[pos*512 + i];
            v = (n & 1) ? (v*ct + p*st) : (v*ct - p*st);
            outQ[(size_t)m*DM + n] = f2bf(v * QSCALE);
          } else if (n < DM + KVD) {       // K
            int nk = n - DM;
            int pos = m & (SEQ-1);
            int i = nk >> 1;
            float ct = rc[pos*512 + i], st = rs[pos*512 + i];
            v = (nk & 1) ? (v*ct + p*st) : (v*ct - p*st);
            outK[(size_t)m*KVD + nk] = f2bf(v);
          } else {                         // V -> transposed Vt[b][nv][s]
            int nv = n - DM - KVD;
            outVt[((size_t)(m >> 10)*KVD + nv)*SEQ + (m & (SEQ-1))] = f2bf(v);
          }
        } else {
          outF[(size_t)m*DM + n] = v + bias[n];
        }
      }
}

// ---- causal GQA flash attention v15: lean single-stream, max occupancy ------
// KVBLK=64, single 16-row q-tile stream per wave -> ~90 VGPR, LDS 16 KB
// (2 x (4KB K + 4KB V)): 4+ blocks/CU co-resident. Pairing (63-y, y): nt sums
// to a uniform 17 iters/block. grid (32,32): x = b*8+hk -> XCD = hk (K/V
// local). K LDS [32 rowpairs][8 slots x 16B], slot = ((kv&1)*4+lg)^(row&7):
// the measured-conflict-free GEMM pattern. V LDS [32 d][64 kv].
// Fixed-reference softmax (P = 2^s, no max tracking). Counted vmcnt(2).

__global__ __launch_bounds__(256, 4)
void attn_kernel(const unsigned short* __restrict__ Qb, const unsigned short* __restrict__ Kb,
                 const unsigned short* __restrict__ Vtb, unsigned short* __restrict__ Ob)
{
  __shared__ __align__(16) unsigned short Kl[2][32*64];   // 4 KB each
  __shared__ __align__(16) unsigned short Vl[2][32*64];   // 4 KB each
  const int tid = threadIdx.x;
  const int w  = tid >> 6, l = tid & 63;
  const int lg = l >> 4, ll = l & 15;
  const int hk = (int)blockIdx.x & 7, b = (int)blockIdx.x >> 3;
  const int h  = hk*4 + w;

  auto stage = [&](int kvt, int bi) {
    const int kv0 = kvt*64;
    {                                     // K: 256 chunks; [rowpair][slot]
      int row = tid >> 3, slot = tid & 7;
      int sp = slot ^ (row & 7);          // involution, pre-applied to source
      int kv = row*2 + (sp >> 2), c = sp & 3;
      load_lds16(&Kb[((size_t)b*SEQ + kv0 + kv)*KVD + hk*32 + c*8],
                 &Kl[bi][(w*64)*8]);
    }
    {                                     // V: 256 chunks (32 d x 8)
      int d = tid >> 3, c = tid & 7, cl = c ^ (d & 7);
      load_lds16(&Vtb[((size_t)b*KVD + hk*32 + d)*SEQ + kv0 + cl*8],
                 &Vl[bi][(w*64)*8]);
    }
  };

#pragma unroll 1
  for (int ph = 0; ph < 2; ++ph) {
    const int qt = ph ? (int)blockIdx.y : 63 - (int)blockIdx.y;   // 16-row tile
    const int nt = (qt + 4) >> 2;         // 64-wide kv tiles needed (causal)
    const int q0 = qt*16;

    // Q as B-operand frag: col q = ll, k = d = lg*8+j  (pre-scaled by QSCALE)
    short8 qf = *(const short8*)&Qb[((size_t)b*SEQ + q0 + ll)*DM + h*32 + (lg<<3)];

    float4v o[2];                         // O^T frag [df]: d=df*16+lg*4+r, q=ll
    float lrow = 0.f;
    o[0] = (float4v){0,0,0,0}; o[1] = (float4v){0,0,0,0};

    WAIT_VM(0);                           // clean ledger (prior stores + qf load)
    stage(0, 0);
    if (1 < nt) stage(1, 1);

#pragma unroll 2
    for (int kvt = 0; kvt < nt; ++kvt) {
      const int bi = kvt & 1;             // static per unrolled body
      if (kvt + 1 < nt) { WAIT_VM(2); }   // stage kvt+1 stays in flight
      else              { WAIT_VM(0); }
      __builtin_amdgcn_s_barrier();

      // ---- all LDS reads for this buffer (K frags + V frags)
      short8 kf[4];
#pragma unroll
      for (int ni = 0; ni < 4; ++ni) {    // kv = ni*16+ll, k-chunk lg
        int row = ni*8 + (ll >> 1);
        int slot = (((ll & 1) << 2) + lg) ^ (row & 7);
        kf[ni] = *(const short8*)&Kl[bi][row*64 + slot*8];
      }
      short4v vf[2][4];
#pragma unroll
      for (int df = 0; df < 2; ++df) {
        int d = df*16 + ll;
#pragma unroll
        for (int ni = 0; ni < 4; ++ni) {
          int ch = (ni*2 + (lg >> 1)) ^ (d & 7);
          vf[df][ni] = *(const short4v*)&Vl[bi][d*64 + (ch << 3) + ((lg & 1) << 2)];
        }
      }
      WAIT_LGKM0;
      SBAR0;
      __builtin_amdgcn_s_barrier();       // all waves done reading buf bi

      if (kvt + 2 < nt) stage(kvt + 2, bi);

      // ---- S^T = K Q^T : lane holds col q=ll, rows kv = ni*16+lg*4+r
      float sc[4][4];
      __builtin_amdgcn_s_setprio(1);
#pragma unroll
      for (int ni = 0; ni < 4; ++ni) {
        float4v s = __builtin_amdgcn_mfma_f32_16x16x32_bf16(kf[ni], qf,
                       (float4v){0,0,0,0}, 0,0,0);
#pragma unroll
        for (int r = 0; r < 4; ++r) sc[ni][r] = s[r];
      }
      __builtin_amdgcn_s_setprio(0);

      if (kvt == nt-1) {                  // causal mask (only last tile)
        int q = q0 + ll;
#pragma unroll
        for (int ni = 0; ni < 4; ++ni)
#pragma unroll
          for (int r = 0; r < 4; ++r) {
            int kv = kvt*64 + ni*16 + lg*4 + r;
            if (kv > q) sc[ni][r] = -1e30f;
          }
      }

      // ---- fixed-reference softmax: P = 2^s, per-lane only (no reduces)
      float s0 = 0.f;
      short4v pf[4];
#pragma unroll
      for (int ni = 0; ni < 4; ++ni) {
        float p0 = fexp2(sc[ni][0]);
        float p1 = fexp2(sc[ni][1]);
        float p2 = fexp2(sc[ni][2]);
        float p3 = fexp2(sc[ni][3]);
        s0 += (p0 + p1) + (p2 + p3);
        union { unsigned int u[2]; short4v s4; } cv;
        cv.u[0] = cvtpk(p0, p1); cv.u[1] = cvtpk(p2, p3);
        pf[ni] = cv.s4;
      }
      lrow += s0;

      // ---- O^T += V^T P
      __builtin_amdgcn_s_setprio(1);
#pragma unroll
      for (int df = 0; df < 2; ++df)
#pragma unroll
        for (int ni = 0; ni < 4; ++ni)
          o[df] = mfma16(vf[df][ni], pf[ni], o[df]);
      __builtin_amdgcn_s_setprio(0);
    }

    // deferred row-sum reduction (across lg only) + normalized store
    float s = lrow;
    s += __shfl_xor(s, 16);
    s += __shfl_xor(s, 32);
    float inv = 1.f / s;
    size_t tok = (size_t)b*SEQ + q0 + ll;
#pragma unroll
    for (int df = 0; df < 2; ++df) {
      short4v sv;
#pragma unroll
      for (int r = 0; r < 4; ++r) sv[r] = (short)f2bf(o[df][r] * inv);
      *(short4v*)&Ob[tok*DM + h*32 + df*16 + lg*4] = sv;
    }
  }
}

// ---- launch -----------------------------------------------------------------

extern "C" void kernel_launch(void* const* d_in, const int* in_sizes, int n_in,
                              void* d_out, int out_size, void* d_ws, size_t ws_size,
                              hipStream_t stream)
{
  const float* x  = (const float*)d_in[0];
  const float* Wq = (const float*)d_in[1];
  const float* Wk = (const float*)d_in[2];
  const float* Wv = (const float*)d_in[3];
  const float* Wo = (const float*)d_in[4];
  const float* bo = (const float*)d_in[5];
  float* out = (float*)d_out;

  char* ws = (char*)d_ws;
  const size_t MB = 1u << 20;
  unsigned short* xb    = (unsigned short*)(ws + 0*MB);   // 8 MB
  unsigned short* Wqkvb = (unsigned short*)(ws + 8*MB);   // 3 MB [1536][1024]
  unsigned short* Wob   = (unsigned short*)(ws + 11*MB);  // 2 MB
  float*          rc    = (float*)(ws + 13*MB);           // 2 MB [1024][512]
  float*          rs    = (float*)(ws + 15*MB);           // 2 MB
  unsigned short* Qb    = (unsigned short*)(ws + 17*MB);  // 8 MB [4096][1024]
  unsigned short* Kb    = (unsigned short*)(ws + 25*MB);  // 2 MB [4096][256]
  unsigned short* Vt    = (unsigned short*)(ws + 27*MB);  // 2 MB [4][256][1024]
  unsigned short* Ob    = (unsigned short*)(ws + 29*MB);  // 8 MB [4096][1024]
  if (ws_size < 37*MB) return;

  {
    const int total = 1703936 + SEQ*512;
    const int blocks = (total + 255) / 256;
    prep_kernel<<<blocks, 256, 0, stream>>>(x, Wq, Wk, Wv, Wo, xb, Wqkvb, Wob, rc, rs);
  }
  // QKV: N=1536 -> GY=24, 768 blocks (3/CU at 48KB LDS)
  gemm_nt<0, 24><<<dim3(768), 256, 0, stream>>>(xb, Wqkvb, Qb, Kb, Vt, nullptr, nullptr, rc, rs);
  // attn: grid x = b*8+hk (XCD = hk), y = pair index
  attn_kernel<<<dim3(32, 32), 256, 0, stream>>>(Qb, Kb, Vt, Ob);
  // out-proj: N=1024 -> GY=16, 512 blocks
  gemm_nt<2, 16><<<dim3(512), 256, 0, stream>>>(Ob, Wob, nullptr, nullptr, nullptr, out, bo, rc, rs);
}